// Round 2
// baseline (4098.686 us; speedup 1.0000x reference)
//
#include <hip/hip_runtime.h>

typedef unsigned int  u32;
typedef unsigned short u16;

// B=8, NS=80, NN=81, H=256, L=2, STEPS=8, VOCAB=30000
#define ROWS 648          // B*NN

__device__ __forceinline__ float sigf(float x){ return 1.0f/(1.0f+__expf(-x)); }
__device__ __forceinline__ float tanh_fast(float x){
  float e = __expf(-2.0f*fabsf(x));
  float r = (1.0f-e)/(1.0f+e);
  return copysignf(r,x);
}
__device__ __forceinline__ u16 f2bf(float f){        // RTNE f32->bf16
  u32 u = __float_as_uint(f);
  u += 0x7FFFu + ((u>>16)&1u);
  return (u16)(u>>16);
}
__device__ __forceinline__ u32 packbf2(float lo, float hi){
  return (u32)f2bf(lo) | ((u32)f2bf(hi)<<16);
}
__device__ __forceinline__ float bf2f(u16 v){ return __uint_as_float(((u32)v)<<16); }
__device__ __forceinline__ float bflo(u32 u){ return __uint_as_float(u<<16); }
__device__ __forceinline__ float bfhi(u32 u){ return __uint_as_float(u & 0xFFFF0000u); }

// fp32 pair (hl,hh) dot bf16-packed weight pair w, accumulate into c
__device__ __forceinline__ float wdot(u32 w, float hl, float hh, float c){
  c = fmaf(hl, bflo(w), c);
  return fmaf(hh, bfhi(w), c);
}

// ---------------- weight packing ----------------------------------------
// gate-quad, k-pair layout: dst[k2*1024 + j*4 + g] = pack(src[2k2][g*256+j], src[2k2+1][g*256+j])
// rows k<256 from A, k>=256 from Bm (for fused [x|h] @ [Wx;Wh]).
__global__ void pack_gates(const float* __restrict__ A, const float* __restrict__ Bm,
                           u32* __restrict__ dst, int Krows){
  int id = blockIdx.x*256 + threadIdx.x;
  int tot = (Krows>>1)*1024;
  if (id >= tot) return;
  int k2 = id >> 10;
  int c  = id & 1023;
  int j = c >> 2, g = c & 3;
  int k0 = 2*k2, k1 = 2*k2+1;
  float v0 = (k0<256) ? A[k0*1024 + g*256 + j] : Bm[(k0-256)*1024 + g*256 + j];
  float v1 = (k1<256) ? A[k1*1024 + g*256 + j] : Bm[(k1-256)*1024 + g*256 + j];
  dst[id] = packbf2(v0, v1);
}

// plain column k-pair pack: dst[k2*ncol+j] = pack(src[2k2][j], src[2k2+1][j])
__global__ void pack_pairs(const float* __restrict__ src, u32* __restrict__ dst,
                           int Kpairs, int ncol){
  int id = blockIdx.x*256 + threadIdx.x;
  if (id >= Kpairs*ncol) return;
  int k2 = id / ncol, j = id - k2*ncol;
  dst[id] = packbf2(src[(2*k2)*ncol + j], src[(2*k2+1)*ncol + j]);
}

__global__ void k_init_p(float* __restrict__ p0){
  int i = blockIdx.x*256 + threadIdx.x;
  if (i < ROWS) p0[i] = ((i % 81)==0) ? 1.0f : 0.0f;
}

// ---------------- K1: statement embedder + X0 precompute ----------------
// One (b,n) token per 256-thread half-block; 2 rows per block. All fp32.
__global__ __launch_bounds__(512) void k_stmt_x0(
    const float* __restrict__ ne, const float* __restrict__ stWx, const float* __restrict__ stb,
    const float* __restrict__ skWx, const float* __restrict__ skb, float4* __restrict__ X0){
  __shared__ float xv[2][256];
  __shared__ float hv[2][256];
  int r = threadIdx.x >> 8, j = threadIdx.x & 255;
  int bn = blockIdx.x*2 + r;                    // 0..639
  xv[r][j] = ne[bn*256 + j];
  __syncthreads();
  // layer 0 (c_prev=0: f gate irrelevant)
  float a0=stb[j], a2=stb[512+j], a3=stb[768+j];
  for (int k=0;k<256;k++){
    float x = xv[r][k];
    const float* w = stWx + k*1024;
    a0 = fmaf(x, w[j], a0); a2 = fmaf(x, w[512+j], a2); a3 = fmaf(x, w[768+j], a3);
  }
  float c = sigf(a0)*tanh_fast(a2);
  float h = sigf(a3)*tanh_fast(c);
  hv[r][j] = h;
  __syncthreads();
  // layer 1
  a0=stb[1024+j]; a2=stb[1536+j]; a3=stb[1792+j];
  const float* W1 = stWx + 256*1024;
  for (int k=0;k<256;k++){
    float x = hv[r][k];
    const float* w = W1 + k*1024;
    a0 = fmaf(x, w[j], a0); a2 = fmaf(x, w[512+j], a2); a3 = fmaf(x, w[768+j], a3);
  }
  c = sigf(a0)*tanh_fast(a2);
  h = sigf(a3)*tanh_fast(c);
  __syncthreads();
  xv[r][j] = h;           // stmt row
  __syncthreads();
  // X0 = stmt @ sk_Wx[0] + sk_b[0]  (all 4 gates)
  float b0=skb[j], b1g=skb[256+j], b2=skb[512+j], b3=skb[768+j];
  for (int k=0;k<256;k++){
    float x = xv[r][k];
    const float* w = skWx + k*1024;
    b0 = fmaf(x, w[j], b0);     b1g = fmaf(x, w[256+j], b1g);
    b2 = fmaf(x, w[512+j], b2); b3 = fmaf(x, w[768+j], b3);
  }
  X0[bn*256 + j] = make_float4(b0,b1g,b2,b3);
}

// ---------------- K3: skip-encoder chains --------------------------------
// block = (start s, batch-pair); 512 threads = 2 rows x 256 lanes.
// h/c kept fp32; weights bf16-packed (pairs along k). skip stored fp32.
__global__ __launch_bounds__(512) void k_skip_chains(
    const float4* __restrict__ X0,
    const uint4* __restrict__ W0, const uint4* __restrict__ W1,
    const float* __restrict__ skb, const float* __restrict__ lnS, const float* __restrict__ lnB,
    float* __restrict__ skip){
  int s = blockIdx.x >> 2;
  if (s >= 80) return;                       // s=80 chain: zero rows (memset)
  int pair = blockIdx.x & 3;
  int r = threadIdx.x >> 8, j = threadIdx.x & 255;
  int b = pair*2 + r;
  __shared__ float h0s[2][256];              // layer0 h (LN'd), fp32
  __shared__ float in1[2][512];              // [h0_new | h1_ln], fp32
  __shared__ float red[2][8];
  h0s[r][j] = 0.f;
  in1[r][j] = 0.f; in1[r][256+j] = 0.f;
  float c0 = 0.f, c1 = 0.f;
  float s1b0 = skb[1024+j], s1b1 = skb[1280+j], s1b2 = skb[1536+j], s1b3 = skb[1792+j];
  float lS0=lnS[j], lS1=lnS[256+j], lS2=lnS[512+j], lS3=lnS[768+j];
  float lB0=lnB[j], lB1=lnB[256+j], lB2=lnB[512+j], lB3=lnB[768+j];
  __syncthreads();
  for (int idx = s; idx < 80; idx++){
    float4 g = X0[(b*80 + idx)*256 + j];
    float a0=g.x, a1=g.y, a2=g.z, a3=g.w;
    #pragma unroll 4
    for (int k2=0;k2<128;k2++){
      float2 hp = *(const float2*)&h0s[r][2*k2];    // LDS broadcast
      uint4 w = W0[k2*256 + j];
      a0 = wdot(w.x, hp.x, hp.y, a0); a1 = wdot(w.y, hp.x, hp.y, a1);
      a2 = wdot(w.z, hp.x, hp.y, a2); a3 = wdot(w.w, hp.x, hp.y, a3);
    }
    float ii = sigf(a0), ff = sigf(a1), gg = tanh_fast(a2), oo = sigf(a3);
    c0 = ff*c0 + ii*gg;
    float h0n = oo*tanh_fast(c0);
    in1[r][j] = h0n;                              // first half of layer1 input
    __syncthreads();
    a0=s1b0; a1=s1b1; a2=s1b2; a3=s1b3;
    #pragma unroll 4
    for (int k2=0;k2<256;k2++){
      float2 hp = *(const float2*)&in1[r][2*k2];
      uint4 w = W1[k2*256 + j];
      a0 = wdot(w.x, hp.x, hp.y, a0); a1 = wdot(w.y, hp.x, hp.y, a1);
      a2 = wdot(w.z, hp.x, hp.y, a2); a3 = wdot(w.w, hp.x, hp.y, a3);
    }
    ii = sigf(a0); ff = sigf(a1); gg = tanh_fast(a2); oo = sigf(a3);
    c1 = ff*c1 + ii*gg;
    float h1n = oo*tanh_fast(c1);
    skip[((b*81 + s)*81 + (idx+1))*256 + j] = h1n;   // pre-LN output, fp32
    // LayerNorm over concat(c0,h0n,c1,h1n) (1024 elems per row)
    float sm = c0 + h0n + c1 + h1n;
    float sq = c0*c0 + h0n*h0n + c1*c1 + h1n*h1n;
    #pragma unroll
    for (int off=32; off; off>>=1){ sm += __shfl_xor(sm, off); sq += __shfl_xor(sq, off); }
    int wv = (threadIdx.x >> 6) & 3;
    if ((threadIdx.x & 63) == 0){ red[r][wv] = sm; red[r][4+wv] = sq; }
    __syncthreads();
    sm = red[r][0]+red[r][1]+red[r][2]+red[r][3];
    sq = red[r][4]+red[r][5]+red[r][6]+red[r][7];
    float mu = sm * (1.0f/1024.0f);
    float var = sq * (1.0f/1024.0f) - mu*mu;
    float rstd = rsqrtf(var + 1e-6f);
    c0 = (c0 - mu)*rstd*lS0 + lB0;
    float h0ln = (h0n - mu)*rstd*lS1 + lB1;
    c1 = (c1 - mu)*rstd*lS2 + lB2;
    float h1ln = (h1n - mu)*rstd*lS3 + lB3;
    h0s[r][j] = h0ln;
    in1[r][256+j] = h1ln;
    __syncthreads();
  }
}

// ---------------- K4: keys = skip @ ws + bs  (bf16 out) ------------------
// one (b,n) per block; m in register-blocked groups of 8; skip fp32 in LDS.
__global__ __launch_bounds__(256) void k_keys(const float* __restrict__ skip,
    const u32* __restrict__ wspk, const float* __restrict__ bs, u16* __restrict__ keys){
  __shared__ float skr[8][256];
  int tid = threadIdx.x;
  int bn = blockIdx.x;
  float bsv = bs[tid];
  const float4* sk4 = (const float4*)skip;
  for (int m0=0; m0<81; m0+=8){
    int mc = (81-m0 < 8) ? (81-m0) : 8;
    for (int i=tid; i<mc*64; i+=256){
      int mm = i>>6, kk = i&63;
      float4 v = sk4[(bn*81 + m0 + mm)*64 + kk];
      skr[mm][4*kk+0]=v.x; skr[mm][4*kk+1]=v.y; skr[mm][4*kk+2]=v.z; skr[mm][4*kk+3]=v.w;
    }
    __syncthreads();
    float acc[8];
    #pragma unroll
    for (int qq=0;qq<8;qq++) acc[qq]=bsv;
    for (int k2=0;k2<128;k2++){
      u32 w = wspk[k2*256+tid];
      float wl = bflo(w), wh = bfhi(w);
      #pragma unroll
      for (int qq=0;qq<8;qq++){
        float2 sv = *(const float2*)&skr[qq][2*k2];
        acc[qq] = fmaf(sv.x, wl, acc[qq]);
        acc[qq] = fmaf(sv.y, wh, acc[qq]);
      }
    }
    for (int qq=0;qq<mc;qq++) keys[(bn*81+m0+qq)*256+tid] = f2bf(acc[qq]);
    __syncthreads();
  }
}

// ---------------- Ka: q = hcat@wk + bk -----------------------------------
__global__ __launch_bounds__(512) void k_q(
    const float* __restrict__ c0g, const float* __restrict__ h0g,
    const float* __restrict__ c1g, const float* __restrict__ h1g,
    const u32* __restrict__ wkp, const float* __restrict__ bk, float* __restrict__ q){
  int r = threadIdx.x>>8, j = threadIdx.x&255;
  int row = blockIdx.x*2 + r;
  __shared__ float fs[2][1024];
  fs[r][j]      = c0g[row*256+j];
  fs[r][256+j]  = h0g[row*256+j];
  fs[r][512+j]  = c1g[row*256+j];
  fs[r][768+j]  = h1g[row*256+j];
  __syncthreads();
  float acc = bk[j];
  #pragma unroll 4
  for (int k2=0;k2<512;k2++){
    float2 hp = *(const float2*)&fs[r][2*k2];
    acc = wdot(wkp[k2*256+j], hp.x, hp.y, acc);
  }
  q[row*256+j] = acc;
}

// ---------------- Kb: logits -> softmax -> t -----------------------------
// mode 0: only m==1; mode 1: m>n || m==80; mode 2: only m==80
__global__ __launch_bounds__(256) void k_attn(
    const float* __restrict__ q, const u16* __restrict__ keys,
    const float* __restrict__ w1, const float* __restrict__ pcur,
    float* __restrict__ t, int mode){
  int bn = blockIdx.x; int n = bn % 81;
  int tid = threadIdx.x;
  float pv = pcur[bn];
  if (pv == 0.0f){
    if (tid < 81) t[bn*81 + tid] = 0.0f;
    return;
  }
  __shared__ float qv[256];
  __shared__ float lg[81];
  qv[tid] = q[bn*256 + tid];
  if (tid < 81) lg[tid] = -3e38f;
  int lane = tid & 63, wv = tid >> 6;
  float w1v0 = w1[lane], w1v1 = w1[64+lane], w1v2 = w1[128+lane], w1v3 = w1[192+lane];
  __syncthreads();
  for (int m = wv; m < 81; m += 4){
    bool um = (mode==0) ? (m==1) : (mode==2) ? (m==80) : (m>n || m==80);
    if (!um) continue;
    const u16* kr = keys + (bn*81+m)*256;
    float acc;
    acc  = tanh_fast(qv[lane]     + bf2f(kr[lane]))     * w1v0;
    acc += tanh_fast(qv[64+lane]  + bf2f(kr[64+lane]))  * w1v1;
    acc += tanh_fast(qv[128+lane] + bf2f(kr[128+lane])) * w1v2;
    acc += tanh_fast(qv[192+lane] + bf2f(kr[192+lane])) * w1v3;
    #pragma unroll
    for (int off=32; off; off>>=1) acc += __shfl_xor(acc, off);
    if (lane==0) lg[m] = acc;      // b1 omitted: softmax-invariant
  }
  __syncthreads();
  if (tid < 64){
    float v1 = lg[tid];
    float v2 = (tid<17) ? lg[64+tid] : -3e38f;
    float mx = fmaxf(v1, v2);
    #pragma unroll
    for (int off=32; off; off>>=1) mx = fmaxf(mx, __shfl_xor(mx, off));
    float e1 = __expf(v1-mx);
    float e2 = (tid<17) ? __expf(v2-mx) : 0.0f;
    float ssum = e1+e2;
    #pragma unroll
    for (int off=32; off; off>>=1) ssum += __shfl_xor(ssum, off);
    float sc = pv / ssum;
    t[bn*81 + tid] = e1*sc;
    if (tid<17) t[bn*81 + 64+tid] = e2*sc;
  }
}

// ---------------- Kc: x_in/prop einsums + ex-LSTM step + new_p -----------
// 4 (b,m) rows per 1024-thread block. skip fp32, states fp32, weights bf16.
__global__ __launch_bounds__(1024) void k_update(
    const float* __restrict__ t, const float* __restrict__ skip,
    const float* __restrict__ c0i, const float* __restrict__ h0i,
    const float* __restrict__ c1i, const float* __restrict__ h1i,
    const uint4* __restrict__ WA, const uint4* __restrict__ WB,
    const float* __restrict__ exb,
    float* __restrict__ c0o, float* __restrict__ h0o,
    float* __restrict__ c1o, float* __restrict__ h1o,
    float* __restrict__ pnext){
  int rr = threadIdx.x >> 8, j = threadIdx.x & 255;
  int row = blockIdx.x*4 + rr;
  int b = row / 81, m = row - b*81;
  __shared__ float tcol[4][81];
  __shared__ float xh[4][512];
  if (j < 81) tcol[rr][j] = t[(b*81 + j)*81 + m];
  __syncthreads();
  float xa=0.f, c0p=0.f, h0p=0.f, c1p=0.f, h1p=0.f, ts=0.f;
  for (int n=0;n<81;n++){
    float tv = tcol[rr][n];
    ts += tv;
    if (tv != 0.0f){
      xa  = fmaf(tv, skip[((b*81+n)*81 + m)*256 + j], xa);
      int st = (b*81+n)*256 + j;
      c0p = fmaf(tv, c0i[st], c0p);
      h0p = fmaf(tv, h0i[st], h0p);
      c1p = fmaf(tv, c1i[st], c1p);
      h1p = fmaf(tv, h1i[st], h1p);
    }
  }
  float inv = 1.0f/(ts + 1e-7f);
  xa*=inv; c0p*=inv; h0p*=inv; c1p*=inv; h1p*=inv;
  if (j==0) pnext[row] = ts;
  xh[rr][j] = xa; xh[rr][256+j] = h0p;
  __syncthreads();
  float a0=exb[j], a1=exb[256+j], a2=exb[512+j], a3=exb[768+j];
  #pragma unroll 4
  for (int k2=0;k2<256;k2++){
    float2 hp = *(const float2*)&xh[rr][2*k2];
    uint4 w = WA[k2*256+j];
    a0=wdot(w.x,hp.x,hp.y,a0); a1=wdot(w.y,hp.x,hp.y,a1);
    a2=wdot(w.z,hp.x,hp.y,a2); a3=wdot(w.w,hp.x,hp.y,a3);
  }
  float c0n = sigf(a1)*c0p + sigf(a0)*tanh_fast(a2);
  float h0n = sigf(a3)*tanh_fast(c0n);
  __syncthreads();
  xh[rr][j] = h0n; xh[rr][256+j] = h1p;
  __syncthreads();
  a0=exb[1024+j]; a1=exb[1280+j]; a2=exb[1536+j]; a3=exb[1792+j];
  #pragma unroll 4
  for (int k2=0;k2<256;k2++){
    float2 hp = *(const float2*)&xh[rr][2*k2];
    uint4 w = WB[k2*256+j];
    a0=wdot(w.x,hp.x,hp.y,a0); a1=wdot(w.y,hp.x,hp.y,a1);
    a2=wdot(w.z,hp.x,hp.y,a2); a3=wdot(w.w,hp.x,hp.y,a3);
  }
  float c1n = sigf(a1)*c1p + sigf(a0)*tanh_fast(a2);
  float h1n = sigf(a3)*tanh_fast(c1n);
  int o = row*256 + j;
  c0o[o]=c0n; h0o[o]=h0n; c1o[o]=c1n; h1o[o]=h1n;
}

// ---------------- K6: out = h_exit @ wo + bo -----------------------------
__global__ __launch_bounds__(256) void k_out(
    const float* __restrict__ h1f, const int* __restrict__ exitIdx,
    const float* __restrict__ wo, const float* __restrict__ bo, float* __restrict__ out){
  __shared__ float hv[8][256];
  int tid = threadIdx.x;
  for (int i = tid; i < 2048; i += 256){
    int b = i >> 8, k = i & 255;
    hv[b][k] = h1f[(b*81 + exitIdx[b])*256 + k];
  }
  __syncthreads();
  int v = blockIdx.x*256 + tid;
  if (v >= 30000) return;
  float acc[8];
  #pragma unroll
  for (int b=0;b<8;b++) acc[b] = bo[v];
  for (int k=0;k<256;k++){
    float w = wo[k*30000 + v];
    #pragma unroll
    for (int b=0;b<8;b++) acc[b] = fmaf(hv[b][k], w, acc[b]);
  }
  #pragma unroll
  for (int b=0;b<8;b++) out[b*30000+v] = acc[b];
}

// ---------------- launch --------------------------------------------------
extern "C" void kernel_launch(void* const* d_in, const int* in_sizes, int n_in,
                              void* d_out, int out_size, void* d_ws, size_t ws_size,
                              hipStream_t stream){
  (void)in_sizes; (void)n_in; (void)out_size;
  const float* ne    = (const float*)d_in[0];
  const int*   exitI = (const int*)d_in[10];
  const float* stWx  = (const float*)d_in[12];
  const float* stb   = (const float*)d_in[14];
  const float* skWx  = (const float*)d_in[15];
  const float* skWh  = (const float*)d_in[16];
  const float* skb   = (const float*)d_in[17];
  const float* lnS   = (const float*)d_in[18];
  const float* lnB   = (const float*)d_in[19];
  const float* exWx  = (const float*)d_in[20];
  const float* exWh  = (const float*)d_in[21];
  const float* exb   = (const float*)d_in[22];
  const float* wk    = (const float*)d_in[23];
  const float* bk    = (const float*)d_in[24];
  const float* wsm   = (const float*)d_in[25];
  const float* bs    = (const float*)d_in[26];
  const float* w1    = (const float*)d_in[27];
  const float* wo    = (const float*)d_in[29];
  const float* bo    = (const float*)d_in[30];
  float* out = (float*)d_out;

  char* w = (char*)d_ws;
  size_t off = 0;
  auto alloc = [&](size_t bytes)->char*{
    char* p = w + off; off += (bytes + 255) & ~size_t(255); return p;
  };
  float4* X0   = (float4*)alloc((size_t)640*256*16);
  u32* W0pk    = (u32*)alloc((size_t)128*1024*4);
  u32* W1pk    = (u32*)alloc((size_t)256*1024*4);
  u32* WApk    = (u32*)alloc((size_t)256*1024*4);
  u32* WBpk    = (u32*)alloc((size_t)256*1024*4);
  u32* wkp     = (u32*)alloc((size_t)512*256*4);
  u32* wspk    = (u32*)alloc((size_t)128*256*4);
  float* skip  = (float*)alloc((size_t)8*81*81*256*4);   // fp32
  u16* keys    = (u16*)alloc((size_t)8*81*81*256*2);     // bf16
  float* qb    = (float*)alloc((size_t)ROWS*256*4);
  float* tb    = (float*)alloc((size_t)ROWS*81*4);
  float* p0    = (float*)alloc(ROWS*4);
  float* p1    = (float*)alloc(ROWS*4);
  float* stA   = (float*)alloc((size_t)4*ROWS*256*4);
  float* stB   = (float*)alloc((size_t)4*ROWS*256*4);
  if (off > ws_size) return;   // workspace too small — surfaces as absmax fail

  const size_t ST = (size_t)ROWS*256;
  float *A_c0=stA, *A_h0=stA+ST, *A_c1=stA+2*ST, *A_h1=stA+3*ST;
  float *B_c0=stB, *B_h0=stB+ST, *B_c1=stB+2*ST, *B_h1=stB+3*ST;

  hipMemsetAsync(skip, 0, (size_t)8*81*81*256*4, stream);
  hipMemsetAsync(stA, 0, (size_t)4*ROWS*256*4, stream);
  k_init_p<<<3,256,0,stream>>>(p0);

  pack_gates<<<512, 256, 0, stream>>>(skWh, skWh, W0pk, 256);                       // Wh0
  pack_gates<<<1024,256, 0, stream>>>(skWx+256*1024, skWh+256*1024, W1pk, 512);     // [Wx1;Wh1]
  pack_gates<<<1024,256, 0, stream>>>(exWx, exWh, WApk, 512);                       // [exWx0;exWh0]
  pack_gates<<<1024,256, 0, stream>>>(exWx+256*1024, exWh+256*1024, WBpk, 512);     // [exWx1;exWh1]
  pack_pairs<<<512, 256, 0, stream>>>(wk, wkp, 512, 256);
  pack_pairs<<<128, 256, 0, stream>>>(wsm, wspk, 128, 256);

  k_stmt_x0<<<320, 512, 0, stream>>>(ne, stWx, stb, skWx, skb, X0);
  k_skip_chains<<<324, 512, 0, stream>>>(X0, (const uint4*)W0pk, (const uint4*)W1pk,
                                         skb, lnS, lnB, skip);
  k_keys<<<648, 256, 0, stream>>>(skip, wspk, bs, keys);

  float* pc = p0; float* pn = p1;
  for (int s=0; s<8; s++){
    float *ic0,*ih0,*ic1,*ih1,*oc0,*oh0,*oc1,*oh1;
    if ((s & 1) == 0){ ic0=A_c0; ih0=A_h0; ic1=A_c1; ih1=A_h1; oc0=B_c0; oh0=B_h0; oc1=B_c1; oh1=B_h1; }
    else             { ic0=B_c0; ih0=B_h0; ic1=B_c1; ih1=B_h1; oc0=A_c0; oh0=A_h0; oc1=A_c1; oh1=A_h1; }
    k_q<<<324, 512, 0, stream>>>(ic0, ih0, ic1, ih1, wkp, bk, qb);
    int mode = (s==0) ? 0 : ((s==7) ? 2 : 1);
    k_attn<<<648, 256, 0, stream>>>(qb, keys, w1, pc, tb, mode);
    k_update<<<162, 1024, 0, stream>>>(tb, skip, ic0, ih0, ic1, ih1,
                                       (const uint4*)WApk, (const uint4*)WBpk, exb,
                                       oc0, oh0, oc1, oh1, pn);
    float* tmp = pc; pc = pn; pn = tmp;
  }
  // final states are in buffer A (step 7 writes A)
  k_out<<<(30000+255)/256, 256, 0, stream>>>(A_h1, exitI, wo, bo, out);
}

// Round 3
// 3732.998 us; speedup vs baseline: 1.0980x; 1.0980x over previous
//
#include <hip/hip_runtime.h>

typedef unsigned int  u32;
typedef unsigned short u16;
typedef float v2f __attribute__((ext_vector_type(2)));

// B=8, NS=80, NN=81, H=256, L=2, STEPS=8, VOCAB=30000
#define ROWS 648          // B*NN

__device__ __forceinline__ float sigf(float x){ return 1.0f/(1.0f+__expf(-x)); }
__device__ __forceinline__ float tanh_fast(float x){
  float e = __expf(-2.0f*fabsf(x));
  float r = (1.0f-e)/(1.0f+e);
  return copysignf(r,x);
}
__device__ __forceinline__ u16 f2bf(float f){        // RTNE f32->bf16
  u32 u = __float_as_uint(f);
  u += 0x7FFFu + ((u>>16)&1u);
  return (u16)(u>>16);
}
__device__ __forceinline__ u32 packbf2(float lo, float hi){
  return (u32)f2bf(lo) | ((u32)f2bf(hi)<<16);
}
__device__ __forceinline__ float bf2f(u16 v){ return __uint_as_float(((u32)v)<<16); }
__device__ __forceinline__ float bflo(u32 u){ return __uint_as_float(u<<16); }
__device__ __forceinline__ float bfhi(u32 u){ return __uint_as_float(u & 0xFFFF0000u); }
__device__ __forceinline__ v2f unpk(u32 w){
  v2f r; r.x = bflo(w); r.y = bfhi(w); return r;
}

// ---------------- weight packing ----------------------------------------
// gate-quad, k-pair layout: dst[k2*1024 + j*4 + g] = pack(src[2k2][g*256+j], src[2k2+1][g*256+j])
__global__ void pack_gates(const float* __restrict__ A, const float* __restrict__ Bm,
                           u32* __restrict__ dst, int Krows){
  int id = blockIdx.x*256 + threadIdx.x;
  int tot = (Krows>>1)*1024;
  if (id >= tot) return;
  int k2 = id >> 10;
  int c  = id & 1023;
  int j = c >> 2, g = c & 3;
  int k0 = 2*k2, k1 = 2*k2+1;
  float v0 = (k0<256) ? A[k0*1024 + g*256 + j] : Bm[(k0-256)*1024 + g*256 + j];
  float v1 = (k1<256) ? A[k1*1024 + g*256 + j] : Bm[(k1-256)*1024 + g*256 + j];
  dst[id] = packbf2(v0, v1);
}

__global__ void pack_pairs(const float* __restrict__ src, u32* __restrict__ dst,
                           int Kpairs, int ncol){
  int id = blockIdx.x*256 + threadIdx.x;
  if (id >= Kpairs*ncol) return;
  int k2 = id / ncol, j = id - k2*ncol;
  dst[id] = packbf2(src[(2*k2)*ncol + j], src[(2*k2+1)*ncol + j]);
}

__global__ void k_init_p(float* __restrict__ p0){
  int i = blockIdx.x*256 + threadIdx.x;
  if (i < ROWS) p0[i] = ((i % 81)==0) ? 1.0f : 0.0f;
}

// ---------------- K1: statement embedder + X0 precompute ----------------
__global__ __launch_bounds__(512) void k_stmt_x0(
    const float* __restrict__ ne, const float* __restrict__ stWx, const float* __restrict__ stb,
    const float* __restrict__ skWx, const float* __restrict__ skb, float4* __restrict__ X0){
  __shared__ float xv[2][256];
  __shared__ float hv[2][256];
  int r = threadIdx.x >> 8, j = threadIdx.x & 255;
  int bn = blockIdx.x*2 + r;                    // 0..639
  xv[r][j] = ne[bn*256 + j];
  __syncthreads();
  float a0=stb[j], a2=stb[512+j], a3=stb[768+j];
  for (int k=0;k<256;k++){
    float x = xv[r][k];
    const float* w = stWx + k*1024;
    a0 = fmaf(x, w[j], a0); a2 = fmaf(x, w[512+j], a2); a3 = fmaf(x, w[768+j], a3);
  }
  float c = sigf(a0)*tanh_fast(a2);
  float h = sigf(a3)*tanh_fast(c);
  hv[r][j] = h;
  __syncthreads();
  a0=stb[1024+j]; a2=stb[1536+j]; a3=stb[1792+j];
  const float* W1 = stWx + 256*1024;
  for (int k=0;k<256;k++){
    float x = hv[r][k];
    const float* w = W1 + k*1024;
    a0 = fmaf(x, w[j], a0); a2 = fmaf(x, w[512+j], a2); a3 = fmaf(x, w[768+j], a3);
  }
  c = sigf(a0)*tanh_fast(a2);
  h = sigf(a3)*tanh_fast(c);
  __syncthreads();
  xv[r][j] = h;           // stmt row
  __syncthreads();
  float b0=skb[j], b1g=skb[256+j], b2=skb[512+j], b3=skb[768+j];
  for (int k=0;k<256;k++){
    float x = xv[r][k];
    const float* w = skWx + k*1024;
    b0 = fmaf(x, w[j], b0);     b1g = fmaf(x, w[256+j], b1g);
    b2 = fmaf(x, w[512+j], b2); b3 = fmaf(x, w[768+j], b3);
  }
  X0[bn*256 + j] = make_float4(b0,b1g,b2,b3);
}

// ---------------- K3: skip-encoder chains --------------------------------
// block = (start s, batch-pair); 512 threads = 2 rows x 256 lanes.
// packed-fp32 (v_pk_fma) gate accumulation; weights bf16 k-pair packed.
// __launch_bounds__(512,4): cap VGPR at 128 so 2 blocks/CU can co-reside.
__global__ __launch_bounds__(512,4) void k_skip_chains(
    const float4* __restrict__ X0,
    const uint4* __restrict__ W0, const uint4* __restrict__ W1,
    const float* __restrict__ skb, const float* __restrict__ lnS, const float* __restrict__ lnB,
    float* __restrict__ skip){
  int s = blockIdx.x >> 2;
  if (s >= 80) return;                       // s=80 chain: zero rows (memset)
  int pair = blockIdx.x & 3;
  int r = threadIdx.x >> 8, j = threadIdx.x & 255;
  int b = pair*2 + r;
  __shared__ float h0s[2][256];              // layer0 h (LN'd), fp32
  __shared__ float in1[2][512];              // [h0_new | h1_ln], fp32
  __shared__ float red[2][8];
  h0s[r][j] = 0.f;
  in1[r][j] = 0.f; in1[r][256+j] = 0.f;
  float c0 = 0.f, c1 = 0.f;
  float s1b0 = skb[1024+j], s1b1 = skb[1280+j], s1b2 = skb[1536+j], s1b3 = skb[1792+j];
  float lS0=lnS[j], lS1=lnS[256+j], lS2=lnS[512+j], lS3=lnS[768+j];
  float lB0=lnB[j], lB1=lnB[256+j], lB2=lnB[512+j], lB3=lnB[768+j];
  __syncthreads();
  for (int idx = s; idx < 80; idx++){
    float4 g = X0[(b*80 + idx)*256 + j];
    v2f A0 = {g.x, 0.f}, A1 = {g.y, 0.f}, A2 = {g.z, 0.f}, A3 = {g.w, 0.f};
    #pragma unroll 8
    for (int k2=0;k2<128;k2++){
      v2f hp = *(const v2f*)&h0s[r][2*k2];    // LDS broadcast
      uint4 w = W0[k2*256 + j];
      A0 += hp*unpk(w.x); A1 += hp*unpk(w.y);
      A2 += hp*unpk(w.z); A3 += hp*unpk(w.w);
    }
    float a0=A0.x+A0.y, a1=A1.x+A1.y, a2=A2.x+A2.y, a3=A3.x+A3.y;
    float ii = sigf(a0), ff = sigf(a1), gg = tanh_fast(a2), oo = sigf(a3);
    c0 = ff*c0 + ii*gg;
    float h0n = oo*tanh_fast(c0);
    in1[r][j] = h0n;                              // first half of layer1 input
    __syncthreads();
    A0 = (v2f){s1b0, 0.f}; A1 = (v2f){s1b1, 0.f};
    A2 = (v2f){s1b2, 0.f}; A3 = (v2f){s1b3, 0.f};
    #pragma unroll 8
    for (int k2=0;k2<256;k2++){
      v2f hp = *(const v2f*)&in1[r][2*k2];
      uint4 w = W1[k2*256 + j];
      A0 += hp*unpk(w.x); A1 += hp*unpk(w.y);
      A2 += hp*unpk(w.z); A3 += hp*unpk(w.w);
    }
    a0=A0.x+A0.y; a1=A1.x+A1.y; a2=A2.x+A2.y; a3=A3.x+A3.y;
    ii = sigf(a0); ff = sigf(a1); gg = tanh_fast(a2); oo = sigf(a3);
    c1 = ff*c1 + ii*gg;
    float h1n = oo*tanh_fast(c1);
    skip[((b*81 + s)*81 + (idx+1))*256 + j] = h1n;   // pre-LN output, fp32
    // LayerNorm over concat(c0,h0n,c1,h1n) (1024 elems per row)
    float sm = c0 + h0n + c1 + h1n;
    float sq = c0*c0 + h0n*h0n + c1*c1 + h1n*h1n;
    #pragma unroll
    for (int off=32; off; off>>=1){ sm += __shfl_xor(sm, off); sq += __shfl_xor(sq, off); }
    int wv = (threadIdx.x >> 6) & 3;
    if ((threadIdx.x & 63) == 0){ red[r][wv] = sm; red[r][4+wv] = sq; }
    __syncthreads();
    sm = red[r][0]+red[r][1]+red[r][2]+red[r][3];
    sq = red[r][4]+red[r][5]+red[r][6]+red[r][7];
    float mu = sm * (1.0f/1024.0f);
    float var = sq * (1.0f/1024.0f) - mu*mu;
    float rstd = rsqrtf(var + 1e-6f);
    c0 = (c0 - mu)*rstd*lS0 + lB0;
    float h0ln = (h0n - mu)*rstd*lS1 + lB1;
    c1 = (c1 - mu)*rstd*lS2 + lB2;
    float h1ln = (h1n - mu)*rstd*lS3 + lB3;
    h0s[r][j] = h0ln;
    in1[r][256+j] = h1ln;
    __syncthreads();
  }
}

// ---------------- K4: keys = skip @ ws + bs  (bf16 out) ------------------
__global__ __launch_bounds__(256) void k_keys(const float* __restrict__ skip,
    const u32* __restrict__ wspk, const float* __restrict__ bs, u16* __restrict__ keys){
  __shared__ float skr[8][256];
  int tid = threadIdx.x;
  int bn = blockIdx.x;
  float bsv = bs[tid];
  const float4* sk4 = (const float4*)skip;
  for (int m0=0; m0<81; m0+=8){
    int mc = (81-m0 < 8) ? (81-m0) : 8;
    for (int i=tid; i<mc*64; i+=256){
      int mm = i>>6, kk = i&63;
      float4 v = sk4[(bn*81 + m0 + mm)*64 + kk];
      skr[mm][4*kk+0]=v.x; skr[mm][4*kk+1]=v.y; skr[mm][4*kk+2]=v.z; skr[mm][4*kk+3]=v.w;
    }
    __syncthreads();
    v2f acc[8];
    #pragma unroll
    for (int qq=0;qq<8;qq++) acc[qq]=(v2f){0.f,0.f};
    for (int k2=0;k2<128;k2++){
      v2f w2 = unpk(wspk[k2*256+tid]);
      #pragma unroll
      for (int qq=0;qq<8;qq++){
        v2f sv = *(const v2f*)&skr[qq][2*k2];
        acc[qq] += sv*w2;
      }
    }
    for (int qq=0;qq<mc;qq++) keys[(bn*81+m0+qq)*256+tid] = f2bf(acc[qq].x+acc[qq].y+bsv);
    __syncthreads();
  }
}

// ---------------- Kb: fused q + logits -> softmax -> t -------------------
// q[b,n] only feeds row (b,n): compute it in-block, skip entirely when p=0.
// mode 0: only m==1; mode 1: m>n || m==80; mode 2: only m==80
__global__ __launch_bounds__(256) void k_attn(
    const float* __restrict__ c0g, const float* __restrict__ h0g,
    const float* __restrict__ c1g, const float* __restrict__ h1g,
    const u32* __restrict__ wkp, const float* __restrict__ bk,
    const u16* __restrict__ keys, const float* __restrict__ w1,
    const float* __restrict__ pcur, float* __restrict__ t, int mode){
  int bn = blockIdx.x; int n = bn % 81;
  int tid = threadIdx.x;
  float pv = pcur[bn];
  if (pv == 0.0f){
    if (tid < 81) t[bn*81 + tid] = 0.0f;
    return;
  }
  __shared__ float hc[1024];
  __shared__ float qv[256];
  __shared__ float lg[81];
  hc[tid]      = c0g[bn*256+tid];
  hc[256+tid]  = h0g[bn*256+tid];
  hc[512+tid]  = c1g[bn*256+tid];
  hc[768+tid]  = h1g[bn*256+tid];
  if (tid < 81) lg[tid] = -3e38f;
  __syncthreads();
  v2f A = {bk[tid], 0.f};
  #pragma unroll 8
  for (int k2=0;k2<512;k2++){
    v2f hp = *(const v2f*)&hc[2*k2];
    A += hp*unpk(wkp[k2*256+tid]);
  }
  qv[tid] = A.x + A.y;
  __syncthreads();
  int lane = tid & 63, wv = tid >> 6;
  float w1v0 = w1[lane], w1v1 = w1[64+lane], w1v2 = w1[128+lane], w1v3 = w1[192+lane];
  for (int m = wv; m < 81; m += 4){
    bool um = (mode==0) ? (m==1) : (mode==2) ? (m==80) : (m>n || m==80);
    if (!um) continue;
    const u16* kr = keys + (bn*81+m)*256;
    float acc;
    acc  = tanh_fast(qv[lane]     + bf2f(kr[lane]))     * w1v0;
    acc += tanh_fast(qv[64+lane]  + bf2f(kr[64+lane]))  * w1v1;
    acc += tanh_fast(qv[128+lane] + bf2f(kr[128+lane])) * w1v2;
    acc += tanh_fast(qv[192+lane] + bf2f(kr[192+lane])) * w1v3;
    #pragma unroll
    for (int off=32; off; off>>=1) acc += __shfl_xor(acc, off);
    if (lane==0) lg[m] = acc;      // b1 omitted: softmax-invariant
  }
  __syncthreads();
  if (tid < 64){
    float v1 = lg[tid];
    float v2 = (tid<17) ? lg[64+tid] : -3e38f;
    float mx = fmaxf(v1, v2);
    #pragma unroll
    for (int off=32; off; off>>=1) mx = fmaxf(mx, __shfl_xor(mx, off));
    float e1 = __expf(v1-mx);
    float e2 = (tid<17) ? __expf(v2-mx) : 0.0f;
    float ssum = e1+e2;
    #pragma unroll
    for (int off=32; off; off>>=1) ssum += __shfl_xor(ssum, off);
    float sc = pv / ssum;
    t[bn*81 + tid] = e1*sc;
    if (tid<17) t[bn*81 + 64+tid] = e2*sc;
  }
}

// ---------------- Kc: x_in/prop einsums + ex-LSTM step + new_p -----------
// 4 (b,m) rows per 1024-thread block. Dead rows (ts==0) skip the LSTM:
// their outputs are unobservable (t[n,*]=p[n]*a=0; revived rows get
// prop-mixture states; h_exit row is alive at the final step).
__global__ __launch_bounds__(1024) void k_update(
    const float* __restrict__ t, const float* __restrict__ skip,
    const float* __restrict__ c0i, const float* __restrict__ h0i,
    const float* __restrict__ c1i, const float* __restrict__ h1i,
    const uint4* __restrict__ WA, const uint4* __restrict__ WB,
    const float* __restrict__ exb,
    float* __restrict__ c0o, float* __restrict__ h0o,
    float* __restrict__ c1o, float* __restrict__ h1o,
    float* __restrict__ pnext){
  int rr = threadIdx.x >> 8, j = threadIdx.x & 255;
  int row = blockIdx.x*4 + rr;
  int b = row / 81, m = row - b*81;
  __shared__ float tcol[4][81];
  __shared__ float xh[4][512];
  if (j < 81) tcol[rr][j] = t[(b*81 + j)*81 + m];
  __syncthreads();
  float xa=0.f, c0p=0.f, h0p=0.f, c1p=0.f, h1p=0.f, ts=0.f;
  for (int n=0;n<81;n++){
    float tv = tcol[rr][n];
    ts += tv;
    if (tv != 0.0f){
      xa  = fmaf(tv, skip[((b*81+n)*81 + m)*256 + j], xa);
      int st = (b*81+n)*256 + j;
      c0p = fmaf(tv, c0i[st], c0p);
      h0p = fmaf(tv, h0i[st], h0p);
      c1p = fmaf(tv, c1i[st], c1p);
      h1p = fmaf(tv, h1i[st], h1p);
    }
  }
  bool alive = (ts != 0.0f);
  float inv = 1.0f/(ts + 1e-7f);
  xa*=inv; c0p*=inv; h0p*=inv; c1p*=inv; h1p*=inv;
  if (j==0) pnext[row] = ts;
  xh[rr][j] = xa; xh[rr][256+j] = h0p;
  __syncthreads();
  float c0n=0.f, h0n=0.f;
  if (alive){
    v2f A0={exb[j],0.f}, A1={exb[256+j],0.f}, A2={exb[512+j],0.f}, A3={exb[768+j],0.f};
    #pragma unroll 8
    for (int k2=0;k2<256;k2++){
      v2f hp = *(const v2f*)&xh[rr][2*k2];
      uint4 w = WA[k2*256+j];
      A0 += hp*unpk(w.x); A1 += hp*unpk(w.y);
      A2 += hp*unpk(w.z); A3 += hp*unpk(w.w);
    }
    float a0=A0.x+A0.y, a1=A1.x+A1.y, a2=A2.x+A2.y, a3=A3.x+A3.y;
    c0n = sigf(a1)*c0p + sigf(a0)*tanh_fast(a2);
    h0n = sigf(a3)*tanh_fast(c0n);
  }
  __syncthreads();
  xh[rr][j] = h0n; xh[rr][256+j] = h1p;
  __syncthreads();
  if (alive){
    v2f A0={exb[1024+j],0.f}, A1={exb[1280+j],0.f}, A2={exb[1536+j],0.f}, A3={exb[1792+j],0.f};
    #pragma unroll 8
    for (int k2=0;k2<256;k2++){
      v2f hp = *(const v2f*)&xh[rr][2*k2];
      uint4 w = WB[k2*256+j];
      A0 += hp*unpk(w.x); A1 += hp*unpk(w.y);
      A2 += hp*unpk(w.z); A3 += hp*unpk(w.w);
    }
    float a0=A0.x+A0.y, a1=A1.x+A1.y, a2=A2.x+A2.y, a3=A3.x+A3.y;
    float c1n = sigf(a1)*c1p + sigf(a0)*tanh_fast(a2);
    float h1n = sigf(a3)*tanh_fast(c1n);
    int o = row*256 + j;
    c0o[o]=c0n; h0o[o]=h0n; c1o[o]=c1n; h1o[o]=h1n;
  }
}

// ---------------- K6: out = h_exit @ wo + bo -----------------------------
__global__ __launch_bounds__(256) void k_out(
    const float* __restrict__ h1f, const int* __restrict__ exitIdx,
    const float* __restrict__ wo, const float* __restrict__ bo, float* __restrict__ out){
  __shared__ float hv[8][256];
  int tid = threadIdx.x;
  for (int i = tid; i < 2048; i += 256){
    int b = i >> 8, k = i & 255;
    hv[b][k] = h1f[(b*81 + exitIdx[b])*256 + k];
  }
  __syncthreads();
  int v = blockIdx.x*256 + tid;
  if (v >= 30000) return;
  float acc[8];
  #pragma unroll
  for (int b=0;b<8;b++) acc[b] = bo[v];
  for (int k=0;k<256;k++){
    float w = wo[k*30000 + v];
    #pragma unroll
    for (int b=0;b<8;b++) acc[b] = fmaf(hv[b][k], w, acc[b]);
  }
  #pragma unroll
  for (int b=0;b<8;b++) out[b*30000+v] = acc[b];
}

// ---------------- launch --------------------------------------------------
extern "C" void kernel_launch(void* const* d_in, const int* in_sizes, int n_in,
                              void* d_out, int out_size, void* d_ws, size_t ws_size,
                              hipStream_t stream){
  (void)in_sizes; (void)n_in; (void)out_size;
  const float* ne    = (const float*)d_in[0];
  const int*   exitI = (const int*)d_in[10];
  const float* stWx  = (const float*)d_in[12];
  const float* stb   = (const float*)d_in[14];
  const float* skWx  = (const float*)d_in[15];
  const float* skWh  = (const float*)d_in[16];
  const float* skb   = (const float*)d_in[17];
  const float* lnS   = (const float*)d_in[18];
  const float* lnB   = (const float*)d_in[19];
  const float* exWx  = (const float*)d_in[20];
  const float* exWh  = (const float*)d_in[21];
  const float* exb   = (const float*)d_in[22];
  const float* wk    = (const float*)d_in[23];
  const float* bk    = (const float*)d_in[24];
  const float* wsm   = (const float*)d_in[25];
  const float* bs    = (const float*)d_in[26];
  const float* w1    = (const float*)d_in[27];
  const float* wo    = (const float*)d_in[29];
  const float* bo    = (const float*)d_in[30];
  float* out = (float*)d_out;

  char* w = (char*)d_ws;
  size_t off = 0;
  auto alloc = [&](size_t bytes)->char*{
    char* p = w + off; off += (bytes + 255) & ~size_t(255); return p;
  };
  float4* X0   = (float4*)alloc((size_t)640*256*16);
  u32* W0pk    = (u32*)alloc((size_t)128*1024*4);
  u32* W1pk    = (u32*)alloc((size_t)256*1024*4);
  u32* WApk    = (u32*)alloc((size_t)256*1024*4);
  u32* WBpk    = (u32*)alloc((size_t)256*1024*4);
  u32* wkp     = (u32*)alloc((size_t)512*256*4);
  u32* wspk    = (u32*)alloc((size_t)128*256*4);
  float* skip  = (float*)alloc((size_t)8*81*81*256*4);   // fp32
  u16* keys    = (u16*)alloc((size_t)8*81*81*256*2);     // bf16
  float* tb    = (float*)alloc((size_t)ROWS*81*4);
  float* p0    = (float*)alloc(ROWS*4);
  float* p1    = (float*)alloc(ROWS*4);
  float* stA   = (float*)alloc((size_t)4*ROWS*256*4);
  float* stB   = (float*)alloc((size_t)4*ROWS*256*4);
  if (off > ws_size) return;   // workspace too small — surfaces as absmax fail

  const size_t ST = (size_t)ROWS*256;
  float *A_c0=stA, *A_h0=stA+ST, *A_c1=stA+2*ST, *A_h1=stA+3*ST;
  float *B_c0=stB, *B_h0=stB+ST, *B_c1=stB+2*ST, *B_h1=stB+3*ST;

  hipMemsetAsync(skip, 0, (size_t)8*81*81*256*4, stream);
  hipMemsetAsync(stA, 0, (size_t)4*ROWS*256*4, stream);
  hipMemsetAsync(stB, 0, (size_t)4*ROWS*256*4, stream);
  k_init_p<<<3,256,0,stream>>>(p0);

  pack_gates<<<512, 256, 0, stream>>>(skWh, skWh, W0pk, 256);                       // Wh0
  pack_gates<<<1024,256, 0, stream>>>(skWx+256*1024, skWh+256*1024, W1pk, 512);     // [Wx1;Wh1]
  pack_gates<<<1024,256, 0, stream>>>(exWx, exWh, WApk, 512);                       // [exWx0;exWh0]
  pack_gates<<<1024,256, 0, stream>>>(exWx+256*1024, exWh+256*1024, WBpk, 512);     // [exWx1;exWh1]
  pack_pairs<<<512, 256, 0, stream>>>(wk, wkp, 512, 256);
  pack_pairs<<<128, 256, 0, stream>>>(wsm, wspk, 128, 256);

  k_stmt_x0<<<320, 512, 0, stream>>>(ne, stWx, stb, skWx, skb, X0);
  k_skip_chains<<<324, 512, 0, stream>>>(X0, (const uint4*)W0pk, (const uint4*)W1pk,
                                         skb, lnS, lnB, skip);
  k_keys<<<648, 256, 0, stream>>>(skip, wspk, bs, keys);

  float* pc = p0; float* pn = p1;
  for (int s=0; s<8; s++){
    float *ic0,*ih0,*ic1,*ih1,*oc0,*oh0,*oc1,*oh1;
    if ((s & 1) == 0){ ic0=A_c0; ih0=A_h0; ic1=A_c1; ih1=A_h1; oc0=B_c0; oh0=B_h0; oc1=B_c1; oh1=B_h1; }
    else             { ic0=B_c0; ih0=B_h0; ic1=B_c1; ih1=B_h1; oc0=A_c0; oh0=A_h0; oc1=A_c1; oh1=A_h1; }
    int mode = (s==0) ? 0 : ((s==7) ? 2 : 1);
    k_attn<<<648, 256, 0, stream>>>(ic0, ih0, ic1, ih1, wkp, bk, keys, w1, pc, tb, mode);
    k_update<<<162, 1024, 0, stream>>>(tb, skip, ic0, ih0, ic1, ih1,
                                       (const uint4*)WApk, (const uint4*)WBpk, exb,
                                       oc0, oh0, oc1, oh1, pn);
    float* tmp = pc; pc = pn; pn = tmp;
  }
  // final states are in buffer A (step 7 writes A)
  k_out<<<(30000+255)/256, 256, 0, stream>>>(A_h1, exitI, wo, bo, out);
}

// Round 4
// 3729.268 us; speedup vs baseline: 1.0991x; 1.0010x over previous
//
#include <hip/hip_runtime.h>

typedef unsigned int  u32;
typedef unsigned short u16;
typedef float v2f __attribute__((ext_vector_type(2)));

// B=8, NS=80, NN=81, H=256, L=2, STEPS=8, VOCAB=30000
#define ROWS 648          // B*NN

__device__ __forceinline__ float sigf(float x){ return 1.0f/(1.0f+__expf(-x)); }
__device__ __forceinline__ float tanh_fast(float x){
  float e = __expf(-2.0f*fabsf(x));
  float r = (1.0f-e)/(1.0f+e);
  return copysignf(r,x);
}
__device__ __forceinline__ u16 f2bf(float f){        // RTNE f32->bf16
  u32 u = __float_as_uint(f);
  u += 0x7FFFu + ((u>>16)&1u);
  return (u16)(u>>16);
}
__device__ __forceinline__ u32 packbf2(float lo, float hi){
  return (u32)f2bf(lo) | ((u32)f2bf(hi)<<16);
}
__device__ __forceinline__ float bf2f(u16 v){ return __uint_as_float(((u32)v)<<16); }
__device__ __forceinline__ float bflo(u32 u){ return __uint_as_float(u<<16); }
__device__ __forceinline__ float bfhi(u32 u){ return __uint_as_float(u & 0xFFFF0000u); }
__device__ __forceinline__ v2f unpk(u32 w){
  v2f r; r.x = bflo(w); r.y = bfhi(w); return r;
}

// ---------------- weight packing ----------------------------------------
// gate-quad, k-pair layout: dst[k2*1024 + j*4 + g] = pack(src[2k2][g*256+j], src[2k2+1][g*256+j])
__global__ void pack_gates(const float* __restrict__ A, const float* __restrict__ Bm,
                           u32* __restrict__ dst, int Krows){
  int id = blockIdx.x*256 + threadIdx.x;
  int tot = (Krows>>1)*1024;
  if (id >= tot) return;
  int k2 = id >> 10;
  int c  = id & 1023;
  int j = c >> 2, g = c & 3;
  int k0 = 2*k2, k1 = 2*k2+1;
  float v0 = (k0<256) ? A[k0*1024 + g*256 + j] : Bm[(k0-256)*1024 + g*256 + j];
  float v1 = (k1<256) ? A[k1*1024 + g*256 + j] : Bm[(k1-256)*1024 + g*256 + j];
  dst[id] = packbf2(v0, v1);
}

__global__ void pack_pairs(const float* __restrict__ src, u32* __restrict__ dst,
                           int Kpairs, int ncol){
  int id = blockIdx.x*256 + threadIdx.x;
  if (id >= Kpairs*ncol) return;
  int k2 = id / ncol, j = id - k2*ncol;
  dst[id] = packbf2(src[(2*k2)*ncol + j], src[(2*k2+1)*ncol + j]);
}

__global__ void k_init_p(float* __restrict__ p0){
  int i = blockIdx.x*256 + threadIdx.x;
  if (i < ROWS) p0[i] = ((i % 81)==0) ? 1.0f : 0.0f;
}

// ---------------- K1: statement embedder + X0 precompute ----------------
__global__ __launch_bounds__(512) void k_stmt_x0(
    const float* __restrict__ ne, const float* __restrict__ stWx, const float* __restrict__ stb,
    const float* __restrict__ skWx, const float* __restrict__ skb, float4* __restrict__ X0){
  __shared__ float xv[2][256];
  __shared__ float hv[2][256];
  int r = threadIdx.x >> 8, j = threadIdx.x & 255;
  int bn = blockIdx.x*2 + r;                    // 0..639
  xv[r][j] = ne[bn*256 + j];
  __syncthreads();
  float a0=stb[j], a2=stb[512+j], a3=stb[768+j];
  for (int k=0;k<256;k++){
    float x = xv[r][k];
    const float* w = stWx + k*1024;
    a0 = fmaf(x, w[j], a0); a2 = fmaf(x, w[512+j], a2); a3 = fmaf(x, w[768+j], a3);
  }
  float c = sigf(a0)*tanh_fast(a2);
  float h = sigf(a3)*tanh_fast(c);
  hv[r][j] = h;
  __syncthreads();
  a0=stb[1024+j]; a2=stb[1536+j]; a3=stb[1792+j];
  const float* W1 = stWx + 256*1024;
  for (int k=0;k<256;k++){
    float x = hv[r][k];
    const float* w = W1 + k*1024;
    a0 = fmaf(x, w[j], a0); a2 = fmaf(x, w[512+j], a2); a3 = fmaf(x, w[768+j], a3);
  }
  c = sigf(a0)*tanh_fast(a2);
  h = sigf(a3)*tanh_fast(c);
  __syncthreads();
  xv[r][j] = h;           // stmt row
  __syncthreads();
  float b0=skb[j], b1g=skb[256+j], b2=skb[512+j], b3=skb[768+j];
  for (int k=0;k<256;k++){
    float x = xv[r][k];
    const float* w = skWx + k*1024;
    b0 = fmaf(x, w[j], b0);     b1g = fmaf(x, w[256+j], b1g);
    b2 = fmaf(x, w[512+j], b2); b3 = fmaf(x, w[768+j], b3);
  }
  X0[bn*256 + j] = make_float4(b0,b1g,b2,b3);
}

// ---------------- K3: skip-encoder chains (v2) ---------------------------
// grid = (s 0..79) x (batch-half); 1024 threads.
//   matvec role: tid = kh*256+j (kh = k-slice 0..3)  — each weight uint4
//     loaded ONCE per block, serves 4 batch rows (acc[4][4] v2f in regs).
//   cell role:   tid = rr*256+j (rr = batch row 0..3) — gate reduce over kh
//     partials in LDS, LSTM cell, LayerNorm.
// States (c0,c1) live per-thread in cell role; h buffers in LDS packed
// [k2][row][2] so matvec reads are wave-broadcast b64s.
__global__ __launch_bounds__(1024) void k_skip_chains(
    const float4* __restrict__ X0,
    const uint4* __restrict__ W0, const uint4* __restrict__ W1,
    const float* __restrict__ skb, const float* __restrict__ lnS, const float* __restrict__ lnB,
    float* __restrict__ skip){
  int s  = blockIdx.x >> 1;
  int bh = blockIdx.x & 1;
  int tid = threadIdx.x;
  int kh = tid >> 8, j = tid & 255;     // matvec role
  int rr = kh;                          // cell role row
  int b  = bh*4 + rr;
  __shared__ float part[16384];         // 64KB [kh][row][gate][j]
  __shared__ float h0buf[128*8];        // [k2][row][2] layer0 input (LN'd h0)
  __shared__ float in1buf[256*8];       // [k2][row][2] layer1 input [h0_raw | h1_ln]
  __shared__ float red[4][8];
  for (int i=tid; i<128*8; i+=1024) h0buf[i]=0.f;
  for (int i=tid; i<256*8; i+=1024) in1buf[i]=0.f;
  float c0=0.f, c1=0.f;                 // state of (row rr, col j)
  float s1b0=skb[1024+j], s1b1=skb[1280+j], s1b2=skb[1536+j], s1b3=skb[1792+j];
  float lS0=lnS[j], lS1=lnS[256+j], lS2=lnS[512+j], lS3=lnS[768+j];
  float lB0=lnB[j], lB1=lnB[256+j], lB2=lnB[512+j], lB3=lnB[768+j];
  __syncthreads();
  for (int idx=s; idx<80; idx++){
    float4 gx = X0[(b*80+idx)*256 + j];     // issue early; used in cell phase
    // ---- layer0 matvec: h0 @ Wh0, k2 slice [kh*32, kh*32+32)
    v2f acc[4][4];
    #pragma unroll
    for (int r4=0;r4<4;r4++){
      #pragma unroll
      for (int g=0;g<4;g++) acc[r4][g]=(v2f){0.f,0.f};
    }
    #pragma unroll 4
    for (int k2=kh*32; k2<kh*32+32; k2++){
      uint4 w = W0[k2*256+j];
      v2f w0=unpk(w.x), w1=unpk(w.y), w2=unpk(w.z), w3=unpk(w.w);
      const float* hb = &h0buf[k2*8];
      #pragma unroll
      for (int r4=0;r4<4;r4++){
        v2f hp = *(const v2f*)&hb[r4*2];
        acc[r4][0] += hp*w0; acc[r4][1] += hp*w1;
        acc[r4][2] += hp*w2; acc[r4][3] += hp*w3;
      }
    }
    #pragma unroll
    for (int r4=0;r4<4;r4++){
      #pragma unroll
      for (int g=0;g<4;g++)
        part[((kh*4+r4)*4+g)*256 + j] = acc[r4][g].x + acc[r4][g].y;
    }
    __syncthreads();
    // ---- layer0 cell (rr, j)
    float a0=gx.x, a1=gx.y, a2=gx.z, a3=gx.w;   // X0 includes sk_b0
    #pragma unroll
    for (int k=0;k<4;k++){
      a0 += part[((k*4+rr)*4+0)*256+j];
      a1 += part[((k*4+rr)*4+1)*256+j];
      a2 += part[((k*4+rr)*4+2)*256+j];
      a3 += part[((k*4+rr)*4+3)*256+j];
    }
    float ii=sigf(a0), ff=sigf(a1), gg=tanh_fast(a2), oo=sigf(a3);
    c0 = ff*c0 + ii*gg;
    float h0n = oo*tanh_fast(c0);
    in1buf[(j>>1)*8 + rr*2 + (j&1)] = h0n;      // raw h0 -> layer1 input half
    __syncthreads();
    // ---- layer1 matvec: [h0_raw|h1_ln] @ [Wx1;Wh1], k2 slice [kh*64, kh*64+64)
    #pragma unroll
    for (int r4=0;r4<4;r4++){
      #pragma unroll
      for (int g=0;g<4;g++) acc[r4][g]=(v2f){0.f,0.f};
    }
    #pragma unroll 4
    for (int k2=kh*64; k2<kh*64+64; k2++){
      uint4 w = W1[k2*256+j];
      v2f w0=unpk(w.x), w1=unpk(w.y), w2=unpk(w.z), w3=unpk(w.w);
      const float* hb = &in1buf[k2*8];
      #pragma unroll
      for (int r4=0;r4<4;r4++){
        v2f hp = *(const v2f*)&hb[r4*2];
        acc[r4][0] += hp*w0; acc[r4][1] += hp*w1;
        acc[r4][2] += hp*w2; acc[r4][3] += hp*w3;
      }
    }
    #pragma unroll
    for (int r4=0;r4<4;r4++){
      #pragma unroll
      for (int g=0;g<4;g++)
        part[((kh*4+r4)*4+g)*256 + j] = acc[r4][g].x + acc[r4][g].y;
    }
    __syncthreads();
    // ---- layer1 cell (rr, j)
    a0=s1b0; a1=s1b1; a2=s1b2; a3=s1b3;
    #pragma unroll
    for (int k=0;k<4;k++){
      a0 += part[((k*4+rr)*4+0)*256+j];
      a1 += part[((k*4+rr)*4+1)*256+j];
      a2 += part[((k*4+rr)*4+2)*256+j];
      a3 += part[((k*4+rr)*4+3)*256+j];
    }
    ii=sigf(a0); ff=sigf(a1); gg=tanh_fast(a2); oo=sigf(a3);
    c1 = ff*c1 + ii*gg;
    float h1n = oo*tanh_fast(c1);
    skip[((b*81 + s)*81 + (idx+1))*256 + j] = h1n;   // pre-LN output
    // ---- LayerNorm over concat(c0,h0n,c1,h1n) per row (1024 elems)
    float sm = c0 + h0n + c1 + h1n;
    float sq = c0*c0 + h0n*h0n + c1*c1 + h1n*h1n;
    #pragma unroll
    for (int off=32; off; off>>=1){ sm += __shfl_xor(sm, off); sq += __shfl_xor(sq, off); }
    int wq = j >> 6;
    if ((j & 63) == 0){ red[rr][wq] = sm; red[rr][4+wq] = sq; }
    __syncthreads();
    sm = red[rr][0]+red[rr][1]+red[rr][2]+red[rr][3];
    sq = red[rr][4]+red[rr][5]+red[rr][6]+red[rr][7];
    float mu = sm * (1.0f/1024.0f);
    float var = sq * (1.0f/1024.0f) - mu*mu;
    float rstd = rsqrtf(var + 1e-6f);
    c0 = (c0 - mu)*rstd*lS0 + lB0;
    float h0ln = (h0n - mu)*rstd*lS1 + lB1;
    c1 = (c1 - mu)*rstd*lS2 + lB2;
    float h1ln = (h1n - mu)*rstd*lS3 + lB3;
    h0buf[(j>>1)*8 + rr*2 + (j&1)] = h0ln;
    in1buf[(128+(j>>1))*8 + rr*2 + (j&1)] = h1ln;
    __syncthreads();
  }
}

// ---------------- K4: keys = skip @ ws + bs  (bf16 out) ------------------
__global__ __launch_bounds__(256) void k_keys(const float* __restrict__ skip,
    const u32* __restrict__ wspk, const float* __restrict__ bs, u16* __restrict__ keys){
  __shared__ float skr[8][256];
  int tid = threadIdx.x;
  int bn = blockIdx.x;
  float bsv = bs[tid];
  const float4* sk4 = (const float4*)skip;
  for (int m0=0; m0<81; m0+=8){
    int mc = (81-m0 < 8) ? (81-m0) : 8;
    for (int i=tid; i<mc*64; i+=256){
      int mm = i>>6, kk = i&63;
      float4 v = sk4[(bn*81 + m0 + mm)*64 + kk];
      skr[mm][4*kk+0]=v.x; skr[mm][4*kk+1]=v.y; skr[mm][4*kk+2]=v.z; skr[mm][4*kk+3]=v.w;
    }
    __syncthreads();
    v2f acc[8];
    #pragma unroll
    for (int qq=0;qq<8;qq++) acc[qq]=(v2f){0.f,0.f};
    for (int k2=0;k2<128;k2++){
      v2f w2 = unpk(wspk[k2*256+tid]);
      #pragma unroll
      for (int qq=0;qq<8;qq++){
        v2f sv = *(const v2f*)&skr[qq][2*k2];
        acc[qq] += sv*w2;
      }
    }
    for (int qq=0;qq<mc;qq++) keys[(bn*81+m0+qq)*256+tid] = f2bf(acc[qq].x+acc[qq].y+bsv);
    __syncthreads();
  }
}

// ---------------- Kb: fused q + logits -> softmax -> t -------------------
// mode 0: only m==1; mode 1: m>n || m==80; mode 2: only m==80
__global__ __launch_bounds__(256) void k_attn(
    const float* __restrict__ c0g, const float* __restrict__ h0g,
    const float* __restrict__ c1g, const float* __restrict__ h1g,
    const u32* __restrict__ wkp, const float* __restrict__ bk,
    const u16* __restrict__ keys, const float* __restrict__ w1,
    const float* __restrict__ pcur, float* __restrict__ t, int mode){
  int bn = blockIdx.x; int n = bn % 81;
  int tid = threadIdx.x;
  float pv = pcur[bn];
  if (pv == 0.0f){
    if (tid < 81) t[bn*81 + tid] = 0.0f;
    return;
  }
  __shared__ float hc[1024];
  __shared__ float qv[256];
  __shared__ float lg[81];
  hc[tid]      = c0g[bn*256+tid];
  hc[256+tid]  = h0g[bn*256+tid];
  hc[512+tid]  = c1g[bn*256+tid];
  hc[768+tid]  = h1g[bn*256+tid];
  if (tid < 81) lg[tid] = -3e38f;
  __syncthreads();
  v2f A = {bk[tid], 0.f};
  #pragma unroll 8
  for (int k2=0;k2<512;k2++){
    v2f hp = *(const v2f*)&hc[2*k2];
    A += hp*unpk(wkp[k2*256+tid]);
  }
  qv[tid] = A.x + A.y;
  __syncthreads();
  int lane = tid & 63, wv = tid >> 6;
  float w1v0 = w1[lane], w1v1 = w1[64+lane], w1v2 = w1[128+lane], w1v3 = w1[192+lane];
  for (int m = wv; m < 81; m += 4){
    bool um = (mode==0) ? (m==1) : (mode==2) ? (m==80) : (m>n || m==80);
    if (!um) continue;
    const u16* kr = keys + (bn*81+m)*256;
    float acc;
    acc  = tanh_fast(qv[lane]     + bf2f(kr[lane]))     * w1v0;
    acc += tanh_fast(qv[64+lane]  + bf2f(kr[64+lane]))  * w1v1;
    acc += tanh_fast(qv[128+lane] + bf2f(kr[128+lane])) * w1v2;
    acc += tanh_fast(qv[192+lane] + bf2f(kr[192+lane])) * w1v3;
    #pragma unroll
    for (int off=32; off; off>>=1) acc += __shfl_xor(acc, off);
    if (lane==0) lg[m] = acc;      // b1 omitted: softmax-invariant
  }
  __syncthreads();
  if (tid < 64){
    float v1 = lg[tid];
    float v2 = (tid<17) ? lg[64+tid] : -3e38f;
    float mx = fmaxf(v1, v2);
    #pragma unroll
    for (int off=32; off; off>>=1) mx = fmaxf(mx, __shfl_xor(mx, off));
    float e1 = __expf(v1-mx);
    float e2 = (tid<17) ? __expf(v2-mx) : 0.0f;
    float ssum = e1+e2;
    #pragma unroll
    for (int off=32; off; off>>=1) ssum += __shfl_xor(ssum, off);
    float sc = pv / ssum;
    t[bn*81 + tid] = e1*sc;
    if (tid<17) t[bn*81 + 64+tid] = e2*sc;
  }
}

// ---------------- Kc: x_in/prop einsums + ex-LSTM step + new_p -----------
__global__ __launch_bounds__(1024) void k_update(
    const float* __restrict__ t, const float* __restrict__ skip,
    const float* __restrict__ c0i, const float* __restrict__ h0i,
    const float* __restrict__ c1i, const float* __restrict__ h1i,
    const uint4* __restrict__ WA, const uint4* __restrict__ WB,
    const float* __restrict__ exb,
    float* __restrict__ c0o, float* __restrict__ h0o,
    float* __restrict__ c1o, float* __restrict__ h1o,
    float* __restrict__ pnext){
  int rr = threadIdx.x >> 8, j = threadIdx.x & 255;
  int row = blockIdx.x*4 + rr;
  int b = row / 81, m = row - b*81;
  __shared__ float tcol[4][81];
  __shared__ float xh[4][512];
  if (j < 81) tcol[rr][j] = t[(b*81 + j)*81 + m];
  __syncthreads();
  float xa=0.f, c0p=0.f, h0p=0.f, c1p=0.f, h1p=0.f, ts=0.f;
  for (int n=0;n<81;n++){
    float tv = tcol[rr][n];
    ts += tv;
    if (tv != 0.0f){
      xa  = fmaf(tv, skip[((b*81+n)*81 + m)*256 + j], xa);
      int st = (b*81+n)*256 + j;
      c0p = fmaf(tv, c0i[st], c0p);
      h0p = fmaf(tv, h0i[st], h0p);
      c1p = fmaf(tv, c1i[st], c1p);
      h1p = fmaf(tv, h1i[st], h1p);
    }
  }
  bool alive = (ts != 0.0f);
  float inv = 1.0f/(ts + 1e-7f);
  xa*=inv; c0p*=inv; h0p*=inv; c1p*=inv; h1p*=inv;
  if (j==0) pnext[row] = ts;
  xh[rr][j] = xa; xh[rr][256+j] = h0p;
  __syncthreads();
  float c0n=0.f, h0n=0.f;
  if (alive){
    v2f A0={exb[j],0.f}, A1={exb[256+j],0.f}, A2={exb[512+j],0.f}, A3={exb[768+j],0.f};
    #pragma unroll 8
    for (int k2=0;k2<256;k2++){
      v2f hp = *(const v2f*)&xh[rr][2*k2];
      uint4 w = WA[k2*256+j];
      A0 += hp*unpk(w.x); A1 += hp*unpk(w.y);
      A2 += hp*unpk(w.z); A3 += hp*unpk(w.w);
    }
    float a0=A0.x+A0.y, a1=A1.x+A1.y, a2=A2.x+A2.y, a3=A3.x+A3.y;
    c0n = sigf(a1)*c0p + sigf(a0)*tanh_fast(a2);
    h0n = sigf(a3)*tanh_fast(c0n);
  }
  __syncthreads();
  xh[rr][j] = h0n; xh[rr][256+j] = h1p;
  __syncthreads();
  if (alive){
    v2f A0={exb[1024+j],0.f}, A1={exb[1280+j],0.f}, A2={exb[1536+j],0.f}, A3={exb[1792+j],0.f};
    #pragma unroll 8
    for (int k2=0;k2<256;k2++){
      v2f hp = *(const v2f*)&xh[rr][2*k2];
      uint4 w = WB[k2*256+j];
      A0 += hp*unpk(w.x); A1 += hp*unpk(w.y);
      A2 += hp*unpk(w.z); A3 += hp*unpk(w.w);
    }
    float a0=A0.x+A0.y, a1=A1.x+A1.y, a2=A2.x+A2.y, a3=A3.x+A3.y;
    float c1n = sigf(a1)*c1p + sigf(a0)*tanh_fast(a2);
    float h1n = sigf(a3)*tanh_fast(c1n);
    int o = row*256 + j;
    c0o[o]=c0n; h0o[o]=h0n; c1o[o]=c1n; h1o[o]=h1n;
  }
}

// ---------------- K6: out = h_exit @ wo + bo -----------------------------
__global__ __launch_bounds__(256) void k_out(
    const float* __restrict__ h1f, const int* __restrict__ exitIdx,
    const float* __restrict__ wo, const float* __restrict__ bo, float* __restrict__ out){
  __shared__ float hv[8][256];
  int tid = threadIdx.x;
  for (int i = tid; i < 2048; i += 256){
    int b = i >> 8, k = i & 255;
    hv[b][k] = h1f[(b*81 + exitIdx[b])*256 + k];
  }
  __syncthreads();
  int v = blockIdx.x*256 + tid;
  if (v >= 30000) return;
  float acc[8];
  #pragma unroll
  for (int b=0;b<8;b++) acc[b] = bo[v];
  for (int k=0;k<256;k++){
    float w = wo[k*30000 + v];
    #pragma unroll
    for (int b=0;b<8;b++) acc[b] = fmaf(hv[b][k], w, acc[b]);
  }
  #pragma unroll
  for (int b=0;b<8;b++) out[b*30000+v] = acc[b];
}

// ---------------- launch --------------------------------------------------
extern "C" void kernel_launch(void* const* d_in, const int* in_sizes, int n_in,
                              void* d_out, int out_size, void* d_ws, size_t ws_size,
                              hipStream_t stream){
  (void)in_sizes; (void)n_in; (void)out_size;
  const float* ne    = (const float*)d_in[0];
  const int*   exitI = (const int*)d_in[10];
  const float* stWx  = (const float*)d_in[12];
  const float* stb   = (const float*)d_in[14];
  const float* skWx  = (const float*)d_in[15];
  const float* skWh  = (const float*)d_in[16];
  const float* skb   = (const float*)d_in[17];
  const float* lnS   = (const float*)d_in[18];
  const float* lnB   = (const float*)d_in[19];
  const float* exWx  = (const float*)d_in[20];
  const float* exWh  = (const float*)d_in[21];
  const float* exb   = (const float*)d_in[22];
  const float* wk    = (const float*)d_in[23];
  const float* bk    = (const float*)d_in[24];
  const float* wsm   = (const float*)d_in[25];
  const float* bs    = (const float*)d_in[26];
  const float* w1    = (const float*)d_in[27];
  const float* wo    = (const float*)d_in[29];
  const float* bo    = (const float*)d_in[30];
  float* out = (float*)d_out;

  char* w = (char*)d_ws;
  size_t off = 0;
  auto alloc = [&](size_t bytes)->char*{
    char* p = w + off; off += (bytes + 255) & ~size_t(255); return p;
  };
  float4* X0   = (float4*)alloc((size_t)640*256*16);
  u32* W0pk    = (u32*)alloc((size_t)128*1024*4);
  u32* W1pk    = (u32*)alloc((size_t)256*1024*4);
  u32* WApk    = (u32*)alloc((size_t)256*1024*4);
  u32* WBpk    = (u32*)alloc((size_t)256*1024*4);
  u32* wkp     = (u32*)alloc((size_t)512*256*4);
  u32* wspk    = (u32*)alloc((size_t)128*256*4);
  float* skip  = (float*)alloc((size_t)8*81*81*256*4);   // fp32
  u16* keys    = (u16*)alloc((size_t)8*81*81*256*2);     // bf16
  float* tb    = (float*)alloc((size_t)ROWS*81*4);
  float* p0    = (float*)alloc(ROWS*4);
  float* p1    = (float*)alloc(ROWS*4);
  float* stA   = (float*)alloc((size_t)4*ROWS*256*4);
  float* stB   = (float*)alloc((size_t)4*ROWS*256*4);
  if (off > ws_size) return;   // workspace too small — surfaces as absmax fail

  const size_t ST = (size_t)ROWS*256;
  float *A_c0=stA, *A_h0=stA+ST, *A_c1=stA+2*ST, *A_h1=stA+3*ST;
  float *B_c0=stB, *B_h0=stB+ST, *B_c1=stB+2*ST, *B_h1=stB+3*ST;

  hipMemsetAsync(skip, 0, (size_t)8*81*81*256*4, stream);
  hipMemsetAsync(stA, 0, (size_t)4*ROWS*256*4, stream);
  hipMemsetAsync(stB, 0, (size_t)4*ROWS*256*4, stream);
  k_init_p<<<3,256,0,stream>>>(p0);

  pack_gates<<<512, 256, 0, stream>>>(skWh, skWh, W0pk, 256);                       // Wh0
  pack_gates<<<1024,256, 0, stream>>>(skWx+256*1024, skWh+256*1024, W1pk, 512);     // [Wx1;Wh1]
  pack_gates<<<1024,256, 0, stream>>>(exWx, exWh, WApk, 512);                       // [exWx0;exWh0]
  pack_gates<<<1024,256, 0, stream>>>(exWx+256*1024, exWh+256*1024, WBpk, 512);     // [exWx1;exWh1]
  pack_pairs<<<512, 256, 0, stream>>>(wk, wkp, 512, 256);
  pack_pairs<<<128, 256, 0, stream>>>(wsm, wspk, 128, 256);

  k_stmt_x0<<<320, 512, 0, stream>>>(ne, stWx, stb, skWx, skb, X0);
  k_skip_chains<<<160, 1024, 0, stream>>>(X0, (const uint4*)W0pk, (const uint4*)W1pk,
                                          skb, lnS, lnB, skip);
  k_keys<<<648, 256, 0, stream>>>(skip, wspk, bs, keys);

  float* pc = p0; float* pn = p1;
  for (int s=0; s<8; s++){
    float *ic0,*ih0,*ic1,*ih1,*oc0,*oh0,*oc1,*oh1;
    if ((s & 1) == 0){ ic0=A_c0; ih0=A_h0; ic1=A_c1; ih1=A_h1; oc0=B_c0; oh0=B_h0; oc1=B_c1; oh1=B_h1; }
    else             { ic0=B_c0; ih0=B_h0; ic1=B_c1; ih1=B_h1; oc0=A_c0; oh0=A_h0; oc1=A_c1; oh1=A_h1; }
    int mode = (s==0) ? 0 : ((s==7) ? 2 : 1);
    k_attn<<<648, 256, 0, stream>>>(ic0, ih0, ic1, ih1, wkp, bk, keys, w1, pc, tb, mode);
    k_update<<<162, 1024, 0, stream>>>(tb, skip, ic0, ih0, ic1, ih1,
                                       (const uint4*)WApk, (const uint4*)WBpk, exb,
                                       oc0, oh0, oc1, oh1, pn);
    float* tmp = pc; pc = pn; pn = tmp;
  }
  // final states are in buffer A (step 7 writes A)
  k_out<<<(30000+255)/256, 256, 0, stream>>>(A_h1, exitI, wo, bo, out);
}